// Round 11
// baseline (728.932 us; speedup 1.0000x reference)
//
#include <hip/hip_runtime.h>
#include <math.h>

// Problem constants
#define B_    32
#define H_IN  161
#define W_IN  1024
#define C1_   32
#define H1_   81
#define W1_   512
#define C2_   32
#define H2_   41
#define W2_   512

#define OUT_X_SZ ((size_t)B_ * C2_ * H2_ * W2_)            // 21,495,808

// ws byte offsets (all 16B-aligned)
// wf2: kh padded to [-2,22] -> 25 slots x 22 frags x 512 = 281600 bf16
// wf1: kh padded to [-2,42] -> 45 slots x 512 = 23040 bf16
#define WF2_B    0u
#define WF1_B    563200u
#define SCSH_B   609280u
#define LENS1_B  609792u
#define XG_B     609920u       // 32*81*512*32 bf16 = 84,934,656 B

#define WF2_N    281600
#define WF1_N    23040

typedef __bf16 v8bf __attribute__((ext_vector_type(8)));
typedef float v16f __attribute__((ext_vector_type(16)));

static __device__ __forceinline__ unsigned short f2bf(float f) {
    unsigned int u = __float_as_uint(f);
    unsigned int r = (u + 0x7fffu + ((u >> 16) & 1u)) >> 16;
    return (unsigned short)r;
}

// ---------------------------------------------------------------------------
// Prep (verified, unchanged): pack conv1+conv2 weights into MFMA A-fragment
// lane order with zero-padded kh halos, fold BN, compute lens.
// ---------------------------------------------------------------------------
__global__ void prep_kernel(const float* __restrict__ w1, const float* __restrict__ b1,
                            const float* __restrict__ g1, const float* __restrict__ be1,
                            const float* __restrict__ m1, const float* __restrict__ v1,
                            const float* __restrict__ w2, const float* __restrict__ b2,
                            const float* __restrict__ g2, const float* __restrict__ be2,
                            const float* __restrict__ m2, const float* __restrict__ v2,
                            const int* __restrict__ lens,
                            unsigned short* __restrict__ wf1, unsigned short* __restrict__ wf2,
                            float* __restrict__ scsh, int* __restrict__ lens1,
                            float* __restrict__ out_lens)
{
    const int i = blockIdx.x * blockDim.x + threadIdx.x;
    const int stride = gridDim.x * blockDim.x;

    for (int idx = i; idx < WF2_N; idx += stride) {
        int j  = idx & 7;
        int l  = (idx >> 3) & 63;
        int f  = idx >> 9;
        int ch = f & 1;
        int kwkh = f >> 1;
        int kw  = kwkh % 11;
        int khp = kwkh / 11;           // 0..24
        int kh  = khp - 2;
        int oc = l & 31;
        int c  = ch * 16 + ((l >> 5) << 3) + j;
        wf2[idx] = (kh >= 0 && kh < 21)
                 ? f2bf(w2[((oc * 32 + c) * 21 + kh) * 11 + kw]) : (unsigned short)0;
    }
    for (int idx = i; idx < WF1_N; idx += stride) {
        int j   = idx & 7;
        int l   = (idx >> 3) & 63;
        int khp = idx >> 9;            // 0..44
        int kh  = khp - 2;
        int k   = ((l >> 5) << 3) + j;
        int oc  = l & 31;
        wf1[idx] = (k < 11 && kh >= 0 && kh < 41)
                 ? f2bf(w1[oc * 451 + kh * 11 + k]) : (unsigned short)0;
    }
    if (i < 32) {
        float s1 = g1[i] / sqrtf(v1[i] + 1e-5f);
        scsh[i]      = s1;
        scsh[32 + i] = b1[i] * s1 + be1[i] - m1[i] * s1;
        float s2 = g2[i] / sqrtf(v2[i] + 1e-5f);
        scsh[64 + i] = s2;
        scsh[96 + i] = b2[i] * s2 + be2[i] - m2[i] * s2;
        int l1 = (lens[i] - 1) / 2 + 1;
        if (l1 > W1_) l1 = W1_;
        lens1[i] = l1;
        out_lens[i] = (float)l1;
    }
}

// ---------------------------------------------------------------------------
// Conv1 v9 (round-7 verified — best conv1): 4 rows per barrier-step.
// Block (w-half 256, h-pair, b), 4 waves. 11 steps; per step: wave wv
// reg-stages row 4(s+1)+wv, all waves compute 4 rows x 4 MFMAs, one barrier.
// ---------------------------------------------------------------------------
__global__ __launch_bounds__(256) void conv1_mfma(
    const float* __restrict__ x,             // [32][1][161][1024]
    const unsigned short* __restrict__ wf1,  // frag-ordered, kh-padded (45)
    const float* __restrict__ scsh,
    const int* __restrict__ lens1,
    unsigned short* __restrict__ xg)         // [32][81][512][32] bf16
{
    const int t    = threadIdx.x;
    const int lane = t & 63;
    const int l31  = lane & 31;
    const int lhi  = lane >> 5;
    const int wv   = t >> 6;
    const int w0   = blockIdx.x * 256;
    const int hp   = blockIdx.y;
    const int b    = blockIdx.z;
    const int h0   = hp * 2;
    const bool h1ok = (h0 + 1) < H1_;

    __shared__ unsigned int srow[2][4][264];   // 8448 B

    v16f acc[2][2];
#pragma unroll
    for (int hh = 0; hh < 2; ++hh)
#pragma unroll
        for (int nt = 0; nt < 2; ++nt)
#pragma unroll
            for (int q = 0; q < 16; ++q) acc[hh][nt][q] = 0.f;

    const int r0 = 2 * h0 - 20;
    const int cb = 2 * w0 - 5;               // global col of packed elem 0
    const float* xb = x + (size_t)b * (H_IN * W_IN);

    const int dwbase = wv * 64 + l31 + 4 * lhi;

    // ---- prologue: wave wv stages row kp=wv (r=r0+wv) into buf0 ----
    {
        const int r = r0 + wv;
        const bool rok = (r >= 0) && (r < H_IN);
        const float* src = xb + (size_t)r * W_IN;
        unsigned int* drow = &srow[0][wv][0];
#pragma unroll
        for (int jj = 0; jj < 4; ++jj) {
            const int cp = lane + 64 * jj;
            const int c  = cb + 2 * cp;
            float a0 = 0.f, a1 = 0.f;
            if (rok) {
                if ((unsigned)c < (unsigned)W_IN)       a0 = src[c];
                if ((unsigned)(c + 1) < (unsigned)W_IN) a1 = src[c + 1];
            }
            drow[cp] = (unsigned int)f2bf(a0) | ((unsigned int)f2bf(a1) << 16);
        }
        if (lane < 8) {
            const int cp = 256 + lane;
            const int c  = cb + 2 * cp;
            float a0 = 0.f, a1 = 0.f;
            if (rok) {
                if ((unsigned)c < (unsigned)W_IN)       a0 = src[c];
                if ((unsigned)(c + 1) < (unsigned)W_IN) a1 = src[c + 1];
            }
            drow[cp] = (unsigned int)f2bf(a0) | ((unsigned int)f2bf(a1) << 16);
        }
    }
    __syncthreads();

    const uint4* wf1q = (const uint4*)wf1;

    for (int s = 0; s < 11; ++s) {
        const int p = s & 1;

        // ---- reg-stage next 4 rows (one per wave), loads issued early ----
        float sa[5][2];
#pragma unroll
        for (int jj = 0; jj < 5; ++jj) { sa[jj][0] = 0.f; sa[jj][1] = 0.f; }
        const int kpn = 4 * (s + 1) + wv;
        const int rn  = r0 + kpn;
        const bool sv = (s < 10) && (kpn < 43) && (rn >= 0) && (rn < H_IN);
        if (sv) {
            const float* src = xb + (size_t)rn * W_IN;
#pragma unroll
            for (int jj = 0; jj < 4; ++jj) {
                const int c = cb + 2 * (lane + 64 * jj);
                if ((unsigned)c < (unsigned)W_IN)       sa[jj][0] = src[c];
                if ((unsigned)(c + 1) < (unsigned)W_IN) sa[jj][1] = src[c + 1];
            }
            if (lane < 8) {
                const int c = cb + 2 * (256 + lane);
                if ((unsigned)c < (unsigned)W_IN)       sa[4][0] = src[c];
                if ((unsigned)(c + 1) < (unsigned)W_IN) sa[4][1] = src[c + 1];
            }
        }

        // ---- compute rows kp = 4s .. 4s+3 on buffer p ----
#pragma unroll
        for (int j = 0; j < 4; ++j) {
            const int kp = 4 * s + j;
            if (kp > 42) break;
            const int r = r0 + kp;
            if (r >= 0 && r < H_IN) {
                uint4 a0u = wf1q[(kp + 2) * 32 + lane];   // h0: kh = kp
                uint4 a1u = wf1q[kp * 32 + lane];         // h1: kh = kp-2 (padded)
                v8bf A0 = __builtin_bit_cast(v8bf, a0u);
                v8bf A1 = __builtin_bit_cast(v8bf, a1u);
                const unsigned int* bp = &srow[p][j][0];
                uint4 bu0, bu1;
                {
                    int dw = dwbase;
                    bu0.x = bp[dw]; bu0.y = bp[dw + 1]; bu0.z = bp[dw + 2]; bu0.w = bp[dw + 3];
                    dw += 32;
                    bu1.x = bp[dw]; bu1.y = bp[dw + 1]; bu1.z = bp[dw + 2]; bu1.w = bp[dw + 3];
                }
                v8bf B0 = __builtin_bit_cast(v8bf, bu0);
                v8bf B1 = __builtin_bit_cast(v8bf, bu1);
                acc[0][0] = __builtin_amdgcn_mfma_f32_32x32x16_bf16(A0, B0, acc[0][0], 0, 0, 0);
                acc[0][1] = __builtin_amdgcn_mfma_f32_32x32x16_bf16(A0, B1, acc[0][1], 0, 0, 0);
                acc[1][0] = __builtin_amdgcn_mfma_f32_32x32x16_bf16(A1, B0, acc[1][0], 0, 0, 0);
                acc[1][1] = __builtin_amdgcn_mfma_f32_32x32x16_bf16(A1, B1, acc[1][1], 0, 0, 0);
            }
        }

        // ---- write staged row into the other buffer, then barrier ----
        if (sv) {
            unsigned int* drow = &srow[p ^ 1][wv][0];
#pragma unroll
            for (int jj = 0; jj < 4; ++jj)
                drow[lane + 64 * jj] =
                    (unsigned int)f2bf(sa[jj][0]) | ((unsigned int)f2bf(sa[jj][1]) << 16);
            if (lane < 8)
                drow[256 + lane] =
                    (unsigned int)f2bf(sa[4][0]) | ((unsigned int)f2bf(sa[4][1]) << 16);
        }
        __syncthreads();
    }

    // ---- epilogue: BN + hardtanh + mask, write xg[b][h][w][c] bf16 ----
    const int l1 = lens1[b];
#pragma unroll
    for (int hh = 0; hh < 2; ++hh) {
        if (hh == 1 && !h1ok) break;
        const int h = h0 + hh;
#pragma unroll
        for (int nt = 0; nt < 2; ++nt) {
            const int w = w0 + wv * 64 + nt * 32 + l31;
            const bool keep = (w < l1);
            unsigned short* dp = xg + (((size_t)b * H1_ + h) * W1_ + w) * 32;
#pragma unroll
            for (int rq = 0; rq < 4; ++rq) {
                unsigned int wd[2];
#pragma unroll
                for (int d = 0; d < 2; ++d) {
                    int rg = rq * 4 + d * 2;
                    int oc = 8 * rq + 4 * lhi + d * 2;
                    float av0 = acc[hh][nt][rg];
                    float av1 = acc[hh][nt][rg + 1];
                    float v0 = fminf(fmaxf(fmaf(av0, scsh[oc],     scsh[32 + oc]), 0.f), 20.f);
                    float v1 = fminf(fmaxf(fmaf(av1, scsh[oc + 1], scsh[33 + oc]), 0.f), 20.f);
                    if (!keep) { v0 = 0.f; v1 = 0.f; }
                    wd[d] = (unsigned int)f2bf(v0) | ((unsigned int)f2bf(v1) << 16);
                }
                uint2 u; u.x = wd[0]; u.y = wd[1];
                *(uint2*)(dp + 8 * rq + 4 * lhi) = u;
            }
        }
    }
}

// ---------------------------------------------------------------------------
// Conv2 v13: wave-specialized + nt=4 A-reuse (the clean A-halving test).
// Block = 256 threads: waves 0-1 = consumers, each owns 128 w (4 m-tiles)
// x h-pair, acc[2][4] (128 VGPR) and ZERO staging state; waves 2-3 =
// producers (v12's byte-identical staging path, 128 threads). Per (kw,ch):
// 2 A-loads feed 8 MFMAs (256 B A per MFMA, was 512) -> A L1 traffic
// 5.6 -> 2.8 GB, below the 143 µs MFMA floor. Same LDS layout (266 pos x
// 80 B, aligned b128), same 1+23 barrier counts on both paths.
// ---------------------------------------------------------------------------
#define ROWB 21280   // 266 positions * 80 B

__global__ __launch_bounds__(256) void conv2_mfma(
    const unsigned short* __restrict__ xg,   // [32][81][512][32] bf16
    const unsigned short* __restrict__ wf2,  // frag-ordered, kh-padded (25)
    const float* __restrict__ scsh,
    const int* __restrict__ lens1,
    float* __restrict__ out)                 // [32][32][41][512] fp32
{
    const int t    = threadIdx.x;
    const int lane = t & 63;
    const int l31  = lane & 31;
    const int lhi  = lane >> 5;
    const int wv   = t >> 6;                 // 0..1 consumers, 2..3 producers

    // bijective XCD swizzle: grid 1344 = 8 * 168
    const int id   = blockIdx.x;
    const int sid  = (id & 7) * 168 + (id >> 3);
    const int wblk = sid & 1;
    const int bh   = sid >> 1;               // 0..671
    const int hp   = bh % 21;
    const int b    = bh / 21;
    const int h0   = hp * 2;
    const bool h1ok = (h0 + 1) < H2_;
    const int w0B  = wblk << 8;

    __shared__ __align__(16) char sbuf[2 * ROWB];

    const unsigned short* xb = xg + (size_t)b * (H1_ * W1_ * 32);
    const int r0 = 2 * h0 - 10;

    if (wv >= 2) {
        // ======================= PRODUCER PATH =======================
        const int pt = t - 128;              // 0..127
        // chunk c = pt + 128*i: pos = c>>2, slot = c&3 (1064 chunks total)

        if (r0 >= 0 && r0 < H1_) {
            const char* xrow = (const char*)(xb + (size_t)r0 * (W1_ * 32));
#pragma unroll
            for (int i = 0; i < 9; ++i) {
                const int c   = pt + 128 * i;
                const int pos = c >> 2;
                const int sg  = c & 3;
                const int wp  = w0B + pos - 5;
                uint4 z; z.x = z.y = z.z = z.w = 0u;
                if (c < 1064 && wp >= 0 && wp < W1_)
                    z = *(const uint4*)(xrow + wp * 64 + sg * 16);
                if (c < 1064)
                    *(uint4*)(sbuf + pos * 80 + sg * 16) = z;
            }
        }
        __syncthreads();

        for (int kp = 0; kp < 23; ++kp) {
            const int p  = kp & 1;
            const int rn = r0 + kp + 1;
            const bool sv = (kp < 22) && (rn >= 0) && (rn < H1_);
            if (sv) {
                const char* xrow = (const char*)(xb + (size_t)rn * (W1_ * 32));
                uint4 g[9];
#pragma unroll
                for (int i = 0; i < 9; ++i) {
                    const int c   = pt + 128 * i;
                    const int pos = c >> 2;
                    const int sg  = c & 3;
                    const int wp  = w0B + pos - 5;
                    g[i].x = g[i].y = g[i].z = g[i].w = 0u;
                    if (c < 1064 && wp >= 0 && wp < W1_)
                        g[i] = *(const uint4*)(xrow + wp * 64 + sg * 16);
                }
                char* db = sbuf + (p ^ 1) * ROWB;
#pragma unroll
                for (int i = 0; i < 9; ++i) {
                    const int c   = pt + 128 * i;
                    const int pos = c >> 2;
                    const int sg  = c & 3;
                    if (c < 1064)
                        *(uint4*)(db + pos * 80 + sg * 16) = g[i];
                }
            }
            __syncthreads();
        }
        // producers exit (no epilogue)
    } else {
        // ======================= CONSUMER PATH =======================
        v16f acc[2][4];
#pragma unroll
        for (int hh = 0; hh < 2; ++hh)
#pragma unroll
            for (int nt = 0; nt < 4; ++nt)
#pragma unroll
                for (int q = 0; q < 16; ++q) acc[hh][nt][q] = 0.f;

        const int rd_lds = (wv * 128 + l31) * 80 + lhi * 16;
        const uint4* wq  = (const uint4*)wf2;

        __syncthreads();                     // matches producer prologue barrier

        for (int kp = 0; kp < 23; ++kp) {
            const int p = kp & 1;
            const int r = r0 + kp;
            if (r >= 0 && r < H1_) {
                // h0: kh = kp (khp0 = kp+2); h1: kh = kp-2 (khp1 = kp) —
                // both always "valid" via zero-padded weights (branch-free).
                const int f0 = (kp + 2) * 22;
                const int f1 = kp * 22;
                const char* bbase = sbuf + p * ROWB + rd_lds;
                __builtin_amdgcn_s_setprio(1);
#pragma unroll
                for (int kw = 0; kw < 11; ++kw) {
#pragma unroll
                    for (int ch = 0; ch < 2; ++ch) {
                        uint4 a0u = wq[(f0 + kw * 2 + ch) * 64 + lane];
                        uint4 a1u = wq[(f1 + kw * 2 + ch) * 64 + lane];
                        v8bf A0 = __builtin_bit_cast(v8bf, a0u);
                        v8bf A1 = __builtin_bit_cast(v8bf, a1u);
                        uint4 b0u = *(const uint4*)(bbase + kw * 80 + ch * 32);
                        uint4 b1u = *(const uint4*)(bbase + 2560 + kw * 80 + ch * 32);
                        uint4 b2u = *(const uint4*)(bbase + 5120 + kw * 80 + ch * 32);
                        uint4 b3u = *(const uint4*)(bbase + 7680 + kw * 80 + ch * 32);
                        v8bf B0 = __builtin_bit_cast(v8bf, b0u);
                        v8bf B1 = __builtin_bit_cast(v8bf, b1u);
                        v8bf B2 = __builtin_bit_cast(v8bf, b2u);
                        v8bf B3 = __builtin_bit_cast(v8bf, b3u);
                        acc[0][0] = __builtin_amdgcn_mfma_f32_32x32x16_bf16(A0, B0, acc[0][0], 0, 0, 0);
                        acc[0][1] = __builtin_amdgcn_mfma_f32_32x32x16_bf16(A0, B1, acc[0][1], 0, 0, 0);
                        acc[0][2] = __builtin_amdgcn_mfma_f32_32x32x16_bf16(A0, B2, acc[0][2], 0, 0, 0);
                        acc[0][3] = __builtin_amdgcn_mfma_f32_32x32x16_bf16(A0, B3, acc[0][3], 0, 0, 0);
                        acc[1][0] = __builtin_amdgcn_mfma_f32_32x32x16_bf16(A1, B0, acc[1][0], 0, 0, 0);
                        acc[1][1] = __builtin_amdgcn_mfma_f32_32x32x16_bf16(A1, B1, acc[1][1], 0, 0, 0);
                        acc[1][2] = __builtin_amdgcn_mfma_f32_32x32x16_bf16(A1, B2, acc[1][2], 0, 0, 0);
                        acc[1][3] = __builtin_amdgcn_mfma_f32_32x32x16_bf16(A1, B3, acc[1][3], 0, 0, 0);
                    }
                }
                __builtin_amdgcn_s_setprio(0);
            }
            __syncthreads();
        }

        // ---- epilogue: BN + hardtanh + mask (consumers only) ----
        const int l2 = lens1[b];
#pragma unroll
        for (int hh = 0; hh < 2; ++hh) {
            if (hh == 1 && !h1ok) break;
            const int h = h0 + hh;
#pragma unroll
            for (int nt = 0; nt < 4; ++nt) {
                const int w = w0B + wv * 128 + nt * 32 + l31;
                const bool keep = (w < l2);
#pragma unroll
                for (int reg = 0; reg < 16; ++reg) {
                    const int oc = (reg & 3) + 8 * (reg >> 2) + 4 * lhi;
                    float v = fmaf(acc[hh][nt][reg], scsh[64 + oc], scsh[96 + oc]);
                    v = fminf(fmaxf(v, 0.f), 20.f);
                    out[(((size_t)b * C2_ + oc) * H2_ + h) * W2_ + w] = keep ? v : 0.f;
                }
            }
        }
    }
}

// ---------------------------------------------------------------------------
extern "C" void kernel_launch(void* const* d_in, const int* in_sizes, int n_in,
                              void* d_out, int out_size, void* d_ws, size_t ws_size,
                              hipStream_t stream) {
    const float* inputs = (const float*)d_in[0];
    const int*   slen   = (const int*)d_in[1];
    const float* w1 = (const float*)d_in[2];
    const float* b1 = (const float*)d_in[3];
    const float* g1 = (const float*)d_in[4];
    const float* be1 = (const float*)d_in[5];
    const float* m1 = (const float*)d_in[6];
    const float* v1 = (const float*)d_in[7];
    const float* w2 = (const float*)d_in[8];
    const float* b2 = (const float*)d_in[9];
    const float* g2 = (const float*)d_in[10];
    const float* be2 = (const float*)d_in[11];
    const float* m2 = (const float*)d_in[12];
    const float* v2 = (const float*)d_in[13];

    char* ws = (char*)d_ws;
    unsigned short* wf2  = (unsigned short*)(ws + WF2_B);
    unsigned short* wf1  = (unsigned short*)(ws + WF1_B);
    float*          scsh = (float*)(ws + SCSH_B);
    int*            lens1 = (int*)(ws + LENS1_B);
    unsigned short* xg   = (unsigned short*)(ws + XG_B);

    float* out_x    = (float*)d_out;
    float* out_lens = out_x + OUT_X_SZ;

    hipLaunchKernelGGL(prep_kernel, dim3(256), dim3(256), 0, stream,
                       w1, b1, g1, be1, m1, v1, w2, b2, g2, be2, m2, v2,
                       slen, wf1, wf2, scsh, lens1, out_lens);

    // conv1: 2 w-halves x 41 h-pairs x 32 b (round-7 verified version)
    hipLaunchKernelGGL(conv1_mfma, dim3(2, 41, B_), dim3(256), 0, stream,
                       inputs, wf1, scsh, lens1, xg);

    // conv2: 32 b * 21 h-pairs * 2 w-halves = 1344 (8*168, XCD-swizzled),
    // 256 threads: 2 consumer + 2 producer waves
    hipLaunchKernelGGL(conv2_mfma, dim3(1344), dim3(256), 0, stream,
                       xg, wf2, scsh, lens1, out_x);
}

// Round 12
// 533.204 us; speedup vs baseline: 1.3671x; 1.3671x over previous
//
#include <hip/hip_runtime.h>
#include <math.h>

// Problem constants
#define B_    32
#define H_IN  161
#define W_IN  1024
#define C1_   32
#define H1_   81
#define W1_   512
#define C2_   32
#define H2_   41
#define W2_   512

#define OUT_X_SZ ((size_t)B_ * C2_ * H2_ * W2_)            // 21,495,808

// ws byte offsets (all 16B-aligned)
// wf2: kh padded to [-2,22] -> 25 slots x 22 frags x 512 = 281600 bf16
// wf1: kh padded to [-2,42] -> 45 slots x 512 = 23040 bf16
#define WF2_B    0u
#define WF1_B    563200u
#define SCSH_B   609280u
#define LENS1_B  609792u
#define XG_B     609920u       // 32*81*512*32 bf16 = 84,934,656 B

#define WF2_N    281600
#define WF1_N    23040

typedef __bf16 v8bf __attribute__((ext_vector_type(8)));
typedef float v16f __attribute__((ext_vector_type(16)));

static __device__ __forceinline__ unsigned short f2bf(float f) {
    unsigned int u = __float_as_uint(f);
    unsigned int r = (u + 0x7fffu + ((u >> 16) & 1u)) >> 16;
    return (unsigned short)r;
}

// ---------------------------------------------------------------------------
// Prep (verified, unchanged): pack conv1+conv2 weights into MFMA A-fragment
// lane order with zero-padded kh halos, fold BN, compute lens.
// ---------------------------------------------------------------------------
__global__ void prep_kernel(const float* __restrict__ w1, const float* __restrict__ b1,
                            const float* __restrict__ g1, const float* __restrict__ be1,
                            const float* __restrict__ m1, const float* __restrict__ v1,
                            const float* __restrict__ w2, const float* __restrict__ b2,
                            const float* __restrict__ g2, const float* __restrict__ be2,
                            const float* __restrict__ m2, const float* __restrict__ v2,
                            const int* __restrict__ lens,
                            unsigned short* __restrict__ wf1, unsigned short* __restrict__ wf2,
                            float* __restrict__ scsh, int* __restrict__ lens1,
                            float* __restrict__ out_lens)
{
    const int i = blockIdx.x * blockDim.x + threadIdx.x;
    const int stride = gridDim.x * blockDim.x;

    for (int idx = i; idx < WF2_N; idx += stride) {
        int j  = idx & 7;
        int l  = (idx >> 3) & 63;
        int f  = idx >> 9;
        int ch = f & 1;
        int kwkh = f >> 1;
        int kw  = kwkh % 11;
        int khp = kwkh / 11;           // 0..24
        int kh  = khp - 2;
        int oc = l & 31;
        int c  = ch * 16 + ((l >> 5) << 3) + j;
        wf2[idx] = (kh >= 0 && kh < 21)
                 ? f2bf(w2[((oc * 32 + c) * 21 + kh) * 11 + kw]) : (unsigned short)0;
    }
    for (int idx = i; idx < WF1_N; idx += stride) {
        int j   = idx & 7;
        int l   = (idx >> 3) & 63;
        int khp = idx >> 9;            // 0..44
        int kh  = khp - 2;
        int k   = ((l >> 5) << 3) + j;
        int oc  = l & 31;
        wf1[idx] = (k < 11 && kh >= 0 && kh < 41)
                 ? f2bf(w1[oc * 451 + kh * 11 + k]) : (unsigned short)0;
    }
    if (i < 32) {
        float s1 = g1[i] / sqrtf(v1[i] + 1e-5f);
        scsh[i]      = s1;
        scsh[32 + i] = b1[i] * s1 + be1[i] - m1[i] * s1;
        float s2 = g2[i] / sqrtf(v2[i] + 1e-5f);
        scsh[64 + i] = s2;
        scsh[96 + i] = b2[i] * s2 + be2[i] - m2[i] * s2;
        int l1 = (lens[i] - 1) / 2 + 1;
        if (l1 > W1_) l1 = W1_;
        lens1[i] = l1;
        out_lens[i] = (float)l1;
    }
}

// ---------------------------------------------------------------------------
// Conv1 v9 (round-7 verified — best conv1): 4 rows per barrier-step.
// ---------------------------------------------------------------------------
__global__ __launch_bounds__(256) void conv1_mfma(
    const float* __restrict__ x,             // [32][1][161][1024]
    const unsigned short* __restrict__ wf1,  // frag-ordered, kh-padded (45)
    const float* __restrict__ scsh,
    const int* __restrict__ lens1,
    unsigned short* __restrict__ xg)         // [32][81][512][32] bf16
{
    const int t    = threadIdx.x;
    const int lane = t & 63;
    const int l31  = lane & 31;
    const int lhi  = lane >> 5;
    const int wv   = t >> 6;
    const int w0   = blockIdx.x * 256;
    const int hp   = blockIdx.y;
    const int b    = blockIdx.z;
    const int h0   = hp * 2;
    const bool h1ok = (h0 + 1) < H1_;

    __shared__ unsigned int srow[2][4][264];   // 8448 B

    v16f acc[2][2];
#pragma unroll
    for (int hh = 0; hh < 2; ++hh)
#pragma unroll
        for (int nt = 0; nt < 2; ++nt)
#pragma unroll
            for (int q = 0; q < 16; ++q) acc[hh][nt][q] = 0.f;

    const int r0 = 2 * h0 - 20;
    const int cb = 2 * w0 - 5;               // global col of packed elem 0
    const float* xb = x + (size_t)b * (H_IN * W_IN);

    const int dwbase = wv * 64 + l31 + 4 * lhi;

    // ---- prologue: wave wv stages row kp=wv (r=r0+wv) into buf0 ----
    {
        const int r = r0 + wv;
        const bool rok = (r >= 0) && (r < H_IN);
        const float* src = xb + (size_t)r * W_IN;
        unsigned int* drow = &srow[0][wv][0];
#pragma unroll
        for (int jj = 0; jj < 4; ++jj) {
            const int cp = lane + 64 * jj;
            const int c  = cb + 2 * cp;
            float a0 = 0.f, a1 = 0.f;
            if (rok) {
                if ((unsigned)c < (unsigned)W_IN)       a0 = src[c];
                if ((unsigned)(c + 1) < (unsigned)W_IN) a1 = src[c + 1];
            }
            drow[cp] = (unsigned int)f2bf(a0) | ((unsigned int)f2bf(a1) << 16);
        }
        if (lane < 8) {
            const int cp = 256 + lane;
            const int c  = cb + 2 * cp;
            float a0 = 0.f, a1 = 0.f;
            if (rok) {
                if ((unsigned)c < (unsigned)W_IN)       a0 = src[c];
                if ((unsigned)(c + 1) < (unsigned)W_IN) a1 = src[c + 1];
            }
            drow[cp] = (unsigned int)f2bf(a0) | ((unsigned int)f2bf(a1) << 16);
        }
    }
    __syncthreads();

    const uint4* wf1q = (const uint4*)wf1;

    for (int s = 0; s < 11; ++s) {
        const int p = s & 1;

        float sa[5][2];
#pragma unroll
        for (int jj = 0; jj < 5; ++jj) { sa[jj][0] = 0.f; sa[jj][1] = 0.f; }
        const int kpn = 4 * (s + 1) + wv;
        const int rn  = r0 + kpn;
        const bool sv = (s < 10) && (kpn < 43) && (rn >= 0) && (rn < H_IN);
        if (sv) {
            const float* src = xb + (size_t)rn * W_IN;
#pragma unroll
            for (int jj = 0; jj < 4; ++jj) {
                const int c = cb + 2 * (lane + 64 * jj);
                if ((unsigned)c < (unsigned)W_IN)       sa[jj][0] = src[c];
                if ((unsigned)(c + 1) < (unsigned)W_IN) sa[jj][1] = src[c + 1];
            }
            if (lane < 8) {
                const int c = cb + 2 * (256 + lane);
                if ((unsigned)c < (unsigned)W_IN)       sa[4][0] = src[c];
                if ((unsigned)(c + 1) < (unsigned)W_IN) sa[4][1] = src[c + 1];
            }
        }

#pragma unroll
        for (int j = 0; j < 4; ++j) {
            const int kp = 4 * s + j;
            if (kp > 42) break;
            const int r = r0 + kp;
            if (r >= 0 && r < H_IN) {
                uint4 a0u = wf1q[(kp + 2) * 32 + lane];   // h0: kh = kp
                uint4 a1u = wf1q[kp * 32 + lane];         // h1: kh = kp-2 (padded)
                v8bf A0 = __builtin_bit_cast(v8bf, a0u);
                v8bf A1 = __builtin_bit_cast(v8bf, a1u);
                const unsigned int* bp = &srow[p][j][0];
                uint4 bu0, bu1;
                {
                    int dw = dwbase;
                    bu0.x = bp[dw]; bu0.y = bp[dw + 1]; bu0.z = bp[dw + 2]; bu0.w = bp[dw + 3];
                    dw += 32;
                    bu1.x = bp[dw]; bu1.y = bp[dw + 1]; bu1.z = bp[dw + 2]; bu1.w = bp[dw + 3];
                }
                v8bf B0 = __builtin_bit_cast(v8bf, bu0);
                v8bf B1 = __builtin_bit_cast(v8bf, bu1);
                acc[0][0] = __builtin_amdgcn_mfma_f32_32x32x16_bf16(A0, B0, acc[0][0], 0, 0, 0);
                acc[0][1] = __builtin_amdgcn_mfma_f32_32x32x16_bf16(A0, B1, acc[0][1], 0, 0, 0);
                acc[1][0] = __builtin_amdgcn_mfma_f32_32x32x16_bf16(A1, B0, acc[1][0], 0, 0, 0);
                acc[1][1] = __builtin_amdgcn_mfma_f32_32x32x16_bf16(A1, B1, acc[1][1], 0, 0, 0);
            }
        }

        if (sv) {
            unsigned int* drow = &srow[p ^ 1][wv][0];
#pragma unroll
            for (int jj = 0; jj < 4; ++jj)
                drow[lane + 64 * jj] =
                    (unsigned int)f2bf(sa[jj][0]) | ((unsigned int)f2bf(sa[jj][1]) << 16);
            if (lane < 8)
                drow[256 + lane] =
                    (unsigned int)f2bf(sa[4][0]) | ((unsigned int)f2bf(sa[4][1]) << 16);
        }
        __syncthreads();
    }

    // ---- epilogue: BN + hardtanh + mask, write xg[b][h][w][c] bf16 ----
    const int l1 = lens1[b];
#pragma unroll
    for (int hh = 0; hh < 2; ++hh) {
        if (hh == 1 && !h1ok) break;
        const int h = h0 + hh;
#pragma unroll
        for (int nt = 0; nt < 2; ++nt) {
            const int w = w0 + wv * 64 + nt * 32 + l31;
            const bool keep = (w < l1);
            unsigned short* dp = xg + (((size_t)b * H1_ + h) * W1_ + w) * 32;
#pragma unroll
            for (int rq = 0; rq < 4; ++rq) {
                unsigned int wd[2];
#pragma unroll
                for (int d = 0; d < 2; ++d) {
                    int rg = rq * 4 + d * 2;
                    int oc = 8 * rq + 4 * lhi + d * 2;
                    float av0 = acc[hh][nt][rg];
                    float av1 = acc[hh][nt][rg + 1];
                    float v0 = fminf(fmaxf(fmaf(av0, scsh[oc],     scsh[32 + oc]), 0.f), 20.f);
                    float v1 = fminf(fmaxf(fmaf(av1, scsh[oc + 1], scsh[33 + oc]), 0.f), 20.f);
                    if (!keep) { v0 = 0.f; v1 = 0.f; }
                    wd[d] = (unsigned int)f2bf(v0) | ((unsigned int)f2bf(v1) << 16);
                }
                uint2 u; u.x = wd[0]; u.y = wd[1];
                *(uint2*)(dp + 8 * rq + 4 * lhi) = u;
            }
        }
    }
}

// ---------------------------------------------------------------------------
// Conv2 v14: 512-thread wave-specialized full-row block.
// Block = (b, h-pair), 8 waves: waves 0-3 = consumers (ONE PER SIMD — v13's
// concentration fixed), each owns 128 w (4 m-tiles) x h-pair, acc[2][4],
// zero staging state. Waves 4-7 = producers staging the full 522-position
// row. SINGLE LDS buffer (41.8 KB) + producer-side register double-buffer,
// 2 barriers/row: producers load row k+1 to regs DURING consumer compute
// (independent waves -> A-pipe/LDS/MFMA overlap, no lockstep), write after
// barrier A. Per consumer per row: 176 MFMAs (A-frag feeds 8 MFMAs).
// 80B-stride LDS (16B-aligned b128). Pipes: MFMA 5632 cyc/SIMD/row >
// L1-A 2816 > LDS 4224 -> MFMA-bound.
// ---------------------------------------------------------------------------
#define ROW2 41760   // 522 positions * 80 B (single buffer)

__global__ __launch_bounds__(512, 2) void conv2_mfma(
    const unsigned short* __restrict__ xg,   // [32][81][512][32] bf16
    const unsigned short* __restrict__ wf2,  // frag-ordered, kh-padded (25)
    const float* __restrict__ scsh,
    const int* __restrict__ lens1,
    float* __restrict__ out)                 // [32][32][41][512] fp32
{
    const int t    = threadIdx.x;
    const int lane = t & 63;
    const int l31  = lane & 31;
    const int lhi  = lane >> 5;
    const int wv   = t >> 6;                 // 0..3 consumers, 4..7 producers

    // bijective XCD swizzle: grid 672 = 8 * 84
    const int id  = blockIdx.x;
    const int sid = (id & 7) * 84 + (id >> 3);
    const int hp  = sid % 21;
    const int b   = sid / 21;
    const int h0  = hp * 2;
    const bool h1ok = (h0 + 1) < H2_;

    __shared__ __align__(16) char sbuf[ROW2];

    const unsigned short* xb = xg + (size_t)b * (H1_ * W1_ * 32);
    const int r0 = 2 * h0 - 10;

    if (wv >= 4) {
        // ======================= PRODUCER PATH =======================
        const int pt = t - 256;              // 0..255
        // 522 pos x 4 slots = 2088 chunks: 8 full rounds + 40 (pt<40).
        // chunk c: pos=c>>2, slot=c&3; src = (pos-5)*64 + slot*16 (zero OOB);
        // lds = pos*80 + slot*16.

        // ---- prologue: stage row r0 (if valid) into the buffer ----
        if (r0 >= 0 && r0 < H1_) {
            const char* xrow = (const char*)(xb + (size_t)r0 * (W1_ * 32));
#pragma unroll
            for (int i = 0; i < 9; ++i) {
                const int c   = pt + 256 * i;
                if (c >= 2088) break;
                const int pos = c >> 2;
                const int sg  = c & 3;
                const int wp  = pos - 5;
                uint4 z; z.x = z.y = z.z = z.w = 0u;
                if (wp >= 0 && wp < W1_)
                    z = *(const uint4*)(xrow + wp * 64 + sg * 16);
                *(uint4*)(sbuf + pos * 80 + sg * 16) = z;
            }
        }
        __syncthreads();                     // buffer ready for kp=0

        for (int kp = 0; kp < 23; ++kp) {
            const int rn = r0 + kp + 1;
            const bool sv = (kp < 22) && (rn >= 0) && (rn < H1_);
            uint4 g[9];
#pragma unroll
            for (int i = 0; i < 9; ++i) { g[i].x = g[i].y = g[i].z = g[i].w = 0u; }
            if (sv) {
                const char* xrow = (const char*)(xb + (size_t)rn * (W1_ * 32));
#pragma unroll
                for (int i = 0; i < 9; ++i) {
                    const int c   = pt + 256 * i;
                    if (c >= 2088) break;
                    const int pos = c >> 2;
                    const int sg  = c & 3;
                    const int wp  = pos - 5;
                    if (wp >= 0 && wp < W1_)
                        g[i] = *(const uint4*)(xrow + wp * 64 + sg * 16);
                }
            }
            __syncthreads();                 // A: consumers done reading row kp
            if (sv) {
#pragma unroll
                for (int i = 0; i < 9; ++i) {
                    const int c   = pt + 256 * i;
                    if (c >= 2088) break;
                    const int pos = c >> 2;
                    const int sg  = c & 3;
                    *(uint4*)(sbuf + pos * 80 + sg * 16) = g[i];
                }
            }
            __syncthreads();                 // B: row kp+1 visible
        }
        // producers exit
    } else {
        // ======================= CONSUMER PATH =======================
        v16f acc[2][4];
#pragma unroll
        for (int hh = 0; hh < 2; ++hh)
#pragma unroll
            for (int nt = 0; nt < 4; ++nt)
#pragma unroll
                for (int q = 0; q < 16; ++q) acc[hh][nt][q] = 0.f;

        const int rd_lds = (wv * 128 + l31) * 80 + lhi * 16;
        const uint4* wq  = (const uint4*)wf2;

        __syncthreads();                     // matches producer prologue barrier

        for (int kp = 0; kp < 23; ++kp) {
            const int r = r0 + kp;
            if (r >= 0 && r < H1_) {
                // h0: kh = kp (khp0 = kp+2); h1: kh = kp-2 (khp1 = kp) —
                // both always "valid" via zero-padded weights (branch-free).
                const int f0 = (kp + 2) * 22;
                const int f1 = kp * 22;
                const char* bbase = sbuf + rd_lds;
                __builtin_amdgcn_s_setprio(1);
#pragma unroll
                for (int kw = 0; kw < 11; ++kw) {
#pragma unroll
                    for (int ch = 0; ch < 2; ++ch) {
                        uint4 a0u = wq[(f0 + kw * 2 + ch) * 64 + lane];
                        uint4 a1u = wq[(f1 + kw * 2 + ch) * 64 + lane];
                        v8bf A0 = __builtin_bit_cast(v8bf, a0u);
                        v8bf A1 = __builtin_bit_cast(v8bf, a1u);
                        uint4 b0u = *(const uint4*)(bbase + kw * 80 + ch * 32);
                        uint4 b1u = *(const uint4*)(bbase + 2560 + kw * 80 + ch * 32);
                        uint4 b2u = *(const uint4*)(bbase + 5120 + kw * 80 + ch * 32);
                        uint4 b3u = *(const uint4*)(bbase + 7680 + kw * 80 + ch * 32);
                        v8bf B0 = __builtin_bit_cast(v8bf, b0u);
                        v8bf B1 = __builtin_bit_cast(v8bf, b1u);
                        v8bf B2 = __builtin_bit_cast(v8bf, b2u);
                        v8bf B3 = __builtin_bit_cast(v8bf, b3u);
                        acc[0][0] = __builtin_amdgcn_mfma_f32_32x32x16_bf16(A0, B0, acc[0][0], 0, 0, 0);
                        acc[0][1] = __builtin_amdgcn_mfma_f32_32x32x16_bf16(A0, B1, acc[0][1], 0, 0, 0);
                        acc[0][2] = __builtin_amdgcn_mfma_f32_32x32x16_bf16(A0, B2, acc[0][2], 0, 0, 0);
                        acc[0][3] = __builtin_amdgcn_mfma_f32_32x32x16_bf16(A0, B3, acc[0][3], 0, 0, 0);
                        acc[1][0] = __builtin_amdgcn_mfma_f32_32x32x16_bf16(A1, B0, acc[1][0], 0, 0, 0);
                        acc[1][1] = __builtin_amdgcn_mfma_f32_32x32x16_bf16(A1, B1, acc[1][1], 0, 0, 0);
                        acc[1][2] = __builtin_amdgcn_mfma_f32_32x32x16_bf16(A1, B2, acc[1][2], 0, 0, 0);
                        acc[1][3] = __builtin_amdgcn_mfma_f32_32x32x16_bf16(A1, B3, acc[1][3], 0, 0, 0);
                    }
                }
                __builtin_amdgcn_s_setprio(0);
            }
            __syncthreads();                 // A
            __syncthreads();                 // B
        }

        // ---- epilogue: BN + hardtanh + mask (consumers only) ----
        const int l2 = lens1[b];
#pragma unroll
        for (int hh = 0; hh < 2; ++hh) {
            if (hh == 1 && !h1ok) break;
            const int h = h0 + hh;
#pragma unroll
            for (int nt = 0; nt < 4; ++nt) {
                const int w = wv * 128 + nt * 32 + l31;
                const bool keep = (w < l2);
#pragma unroll
                for (int reg = 0; reg < 16; ++reg) {
                    const int oc = (reg & 3) + 8 * (reg >> 2) + 4 * lhi;
                    float v = fmaf(acc[hh][nt][reg], scsh[64 + oc], scsh[96 + oc]);
                    v = fminf(fmaxf(v, 0.f), 20.f);
                    out[(((size_t)b * C2_ + oc) * H2_ + h) * W2_ + w] = keep ? v : 0.f;
                }
            }
        }
    }
}

// ---------------------------------------------------------------------------
extern "C" void kernel_launch(void* const* d_in, const int* in_sizes, int n_in,
                              void* d_out, int out_size, void* d_ws, size_t ws_size,
                              hipStream_t stream) {
    const float* inputs = (const float*)d_in[0];
    const int*   slen   = (const int*)d_in[1];
    const float* w1 = (const float*)d_in[2];
    const float* b1 = (const float*)d_in[3];
    const float* g1 = (const float*)d_in[4];
    const float* be1 = (const float*)d_in[5];
    const float* m1 = (const float*)d_in[6];
    const float* v1 = (const float*)d_in[7];
    const float* w2 = (const float*)d_in[8];
    const float* b2 = (const float*)d_in[9];
    const float* g2 = (const float*)d_in[10];
    const float* be2 = (const float*)d_in[11];
    const float* m2 = (const float*)d_in[12];
    const float* v2 = (const float*)d_in[13];

    char* ws = (char*)d_ws;
    unsigned short* wf2  = (unsigned short*)(ws + WF2_B);
    unsigned short* wf1  = (unsigned short*)(ws + WF1_B);
    float*          scsh = (float*)(ws + SCSH_B);
    int*            lens1 = (int*)(ws + LENS1_B);
    unsigned short* xg   = (unsigned short*)(ws + XG_B);

    float* out_x    = (float*)d_out;
    float* out_lens = out_x + OUT_X_SZ;

    hipLaunchKernelGGL(prep_kernel, dim3(256), dim3(256), 0, stream,
                       w1, b1, g1, be1, m1, v1, w2, b2, g2, be2, m2, v2,
                       slen, wf1, wf2, scsh, lens1, out_lens);

    // conv1: 2 w-halves x 41 h-pairs x 32 b (round-7 verified version)
    hipLaunchKernelGGL(conv1_mfma, dim3(2, 41, B_), dim3(256), 0, stream,
                       inputs, wf1, scsh, lens1, xg);

    // conv2: 32 b * 21 h-pairs = 672 blocks (8*84, XCD-swizzled),
    // 512 threads: 4 consumer waves (one per SIMD) + 4 producer waves
    hipLaunchKernelGGL(conv2_mfma, dim3(672), dim3(512), 0, stream,
                       xg, wf2, scsh, lens1, out_x);
}

// Round 13
// 518.595 us; speedup vs baseline: 1.4056x; 1.0282x over previous
//
#include <hip/hip_runtime.h>
#include <math.h>

// Problem constants
#define B_    32
#define H_IN  161
#define W_IN  1024
#define C1_   32
#define H1_   81
#define W1_   512
#define C2_   32
#define H2_   41
#define W2_   512

#define OUT_X_SZ ((size_t)B_ * C2_ * H2_ * W2_)            // 21,495,808

// ws byte offsets (all 16B-aligned)
// wf2: kh padded to [-2,22] -> 25 slots x 22 frags x 512 = 281600 bf16
// wf1: kh padded to [-2,42] -> 45 slots x 512 = 23040 bf16
#define WF2_B    0u
#define WF1_B    563200u
#define SCSH_B   609280u
#define LENS1_B  609792u
#define XG_B     609920u       // 32*81*512*32 bf16 = 84,934,656 B

#define WF2_N    281600
#define WF1_N    23040

// pre-packed conv1 input: xpk[b][r][j] (uint = 2 bf16), j=0..519
// xpk[j] = pack(x[2j-5], x[2j-4]) with per-element zero for OOB.
// Lives in d_out scratch (10.72 MB): written by xcvt, read by conv1,
// fully overwritten by conv2's output afterwards (stream-ordered).
#define XPW 520

typedef __bf16 v8bf __attribute__((ext_vector_type(8)));
typedef float v16f __attribute__((ext_vector_type(16)));

static __device__ __forceinline__ unsigned short f2bf(float f) {
    unsigned int u = __float_as_uint(f);
    unsigned int r = (u + 0x7fffu + ((u >> 16) & 1u)) >> 16;
    return (unsigned short)r;
}

// ---------------------------------------------------------------------------
// Prep (verified, unchanged): pack conv1+conv2 weights into MFMA A-fragment
// lane order with zero-padded kh halos, fold BN, compute lens.
// ---------------------------------------------------------------------------
__global__ void prep_kernel(const float* __restrict__ w1, const float* __restrict__ b1,
                            const float* __restrict__ g1, const float* __restrict__ be1,
                            const float* __restrict__ m1, const float* __restrict__ v1,
                            const float* __restrict__ w2, const float* __restrict__ b2,
                            const float* __restrict__ g2, const float* __restrict__ be2,
                            const float* __restrict__ m2, const float* __restrict__ v2,
                            const int* __restrict__ lens,
                            unsigned short* __restrict__ wf1, unsigned short* __restrict__ wf2,
                            float* __restrict__ scsh, int* __restrict__ lens1,
                            float* __restrict__ out_lens)
{
    const int i = blockIdx.x * blockDim.x + threadIdx.x;
    const int stride = gridDim.x * blockDim.x;

    for (int idx = i; idx < WF2_N; idx += stride) {
        int j  = idx & 7;
        int l  = (idx >> 3) & 63;
        int f  = idx >> 9;
        int ch = f & 1;
        int kwkh = f >> 1;
        int kw  = kwkh % 11;
        int khp = kwkh / 11;           // 0..24
        int kh  = khp - 2;
        int oc = l & 31;
        int c  = ch * 16 + ((l >> 5) << 3) + j;
        wf2[idx] = (kh >= 0 && kh < 21)
                 ? f2bf(w2[((oc * 32 + c) * 21 + kh) * 11 + kw]) : (unsigned short)0;
    }
    for (int idx = i; idx < WF1_N; idx += stride) {
        int j   = idx & 7;
        int l   = (idx >> 3) & 63;
        int khp = idx >> 9;            // 0..44
        int kh  = khp - 2;
        int k   = ((l >> 5) << 3) + j;
        int oc  = l & 31;
        wf1[idx] = (k < 11 && kh >= 0 && kh < 41)
                 ? f2bf(w1[oc * 451 + kh * 11 + k]) : (unsigned short)0;
    }
    if (i < 32) {
        float s1 = g1[i] / sqrtf(v1[i] + 1e-5f);
        scsh[i]      = s1;
        scsh[32 + i] = b1[i] * s1 + be1[i] - m1[i] * s1;
        float s2 = g2[i] / sqrtf(v2[i] + 1e-5f);
        scsh[64 + i] = s2;
        scsh[96 + i] = b2[i] * s2 + be2[i] - m2[i] * s2;
        int l1 = (lens[i] - 1) / 2 + 1;
        if (l1 > W1_) l1 = W1_;
        lens1[i] = l1;
        out_lens[i] = (float)l1;
    }
}

// ---------------------------------------------------------------------------
// xcvt: one-shot fp32 -> packed bf16 odd-pair rows. Removes the 11x-repeated
// scalar-load + f2bf conversion from conv1's hot loop.
// xpk[b][r][j] = pack(x[2j-5], x[2j-4]) (zero for OOB elements).
// With j = 256*half + cp this equals srow[cp] for w-half `half`.
// ---------------------------------------------------------------------------
__global__ __launch_bounds__(256) void xcvt_kernel(
    const float* __restrict__ x,            // [32][1][161][1024]
    unsigned int* __restrict__ xpk)         // [32*161][520]
{
    const int br = blockIdx.x;              // 0..5151 (b*161 + r)
    const int t  = threadIdx.x;
    const float* src = x + (size_t)br * W_IN;
    unsigned int* dst = xpk + (size_t)br * XPW;
    for (int j = t; j < XPW; j += 256) {
        const int c0 = 2 * j - 5;
        const int c1 = 2 * j - 4;
        float a0 = ((unsigned)c0 < (unsigned)W_IN) ? src[c0] : 0.f;
        float a1 = ((unsigned)c1 < (unsigned)W_IN) ? src[c1] : 0.f;
        dst[j] = (unsigned int)f2bf(a0) | ((unsigned int)f2bf(a1) << 16);
    }
}

// ---------------------------------------------------------------------------
// Conv1 v15: v9 skeleton (4 rows per barrier-step, verified) with staging
// replaced by aligned uint4 copies from xpk — no scalar loads, no f2bf,
// no bounds math in the hot loop. Per row per wave: 1 uint4 load (+2-lane
// tail) + 1 ds_write_b128 (+tail).
// ---------------------------------------------------------------------------
__global__ __launch_bounds__(256) void conv1_mfma(
    const unsigned int* __restrict__ xpk,    // [32*161][520] packed pairs
    const unsigned short* __restrict__ wf1,  // frag-ordered, kh-padded (45)
    const float* __restrict__ scsh,
    const int* __restrict__ lens1,
    unsigned short* __restrict__ xg)         // [32][81][512][32] bf16
{
    const int t    = threadIdx.x;
    const int lane = t & 63;
    const int l31  = lane & 31;
    const int lhi  = lane >> 5;
    const int wv   = t >> 6;
    const int half = blockIdx.x;             // 0..1
    const int hp   = blockIdx.y;
    const int b    = blockIdx.z;
    const int h0   = hp * 2;
    const bool h1ok = (h0 + 1) < H1_;
    const int w0   = half * 256;
    const int j0   = half * 256;             // uint offset into xpk row

    __shared__ unsigned int srow[2][4][264];   // 8448 B

    v16f acc[2][2];
#pragma unroll
    for (int hh = 0; hh < 2; ++hh)
#pragma unroll
        for (int nt = 0; nt < 2; ++nt)
#pragma unroll
            for (int q = 0; q < 16; ++q) acc[hh][nt][q] = 0.f;

    const int r0 = 2 * h0 - 20;
    const unsigned int* xpb = xpk + (size_t)b * (H_IN * XPW) + j0;

    const int dwbase = wv * 64 + l31 + 4 * lhi;

    // ---- prologue: wave wv stages row kp=wv (r=r0+wv) into buf0 ----
    {
        const int r = r0 + wv;
        const bool rok = (r >= 0) && (r < H_IN);
        uint4 m; m.x = m.y = m.z = m.w = 0u;
        uint4 e; e.x = e.y = e.z = e.w = 0u;
        if (rok) {
            const unsigned int* xrow = xpb + (size_t)r * XPW;
            m = *(const uint4*)(xrow + 4 * lane);
            if (lane < 2) e = *(const uint4*)(xrow + 256 + 4 * lane);
        }
        *(uint4*)(&srow[0][wv][4 * lane]) = m;
        if (lane < 2) *(uint4*)(&srow[0][wv][256 + 4 * lane]) = e;
    }
    __syncthreads();

    const uint4* wf1q = (const uint4*)wf1;

    for (int s = 0; s < 11; ++s) {
        const int p = s & 1;

        // ---- stage next 4 rows (one per wave): aligned uint4 copies ----
        uint4 m; m.x = m.y = m.z = m.w = 0u;
        uint4 e; e.x = e.y = e.z = e.w = 0u;
        const int kpn = 4 * (s + 1) + wv;
        const int rn  = r0 + kpn;
        const bool sv = (s < 10) && (kpn < 43) && (rn >= 0) && (rn < H_IN);
        if (sv) {
            const unsigned int* xrow = xpb + (size_t)rn * XPW;
            m = *(const uint4*)(xrow + 4 * lane);
            if (lane < 2) e = *(const uint4*)(xrow + 256 + 4 * lane);
        }

        // ---- compute rows kp = 4s .. 4s+3 on buffer p ----
#pragma unroll
        for (int j = 0; j < 4; ++j) {
            const int kp = 4 * s + j;
            if (kp > 42) break;
            const int r = r0 + kp;
            if (r >= 0 && r < H_IN) {
                uint4 a0u = wf1q[(kp + 2) * 32 + lane];   // h0: kh = kp
                uint4 a1u = wf1q[kp * 32 + lane];         // h1: kh = kp-2 (padded)
                v8bf A0 = __builtin_bit_cast(v8bf, a0u);
                v8bf A1 = __builtin_bit_cast(v8bf, a1u);
                const unsigned int* bp = &srow[p][j][0];
                uint4 bu0, bu1;
                {
                    int dw = dwbase;
                    bu0.x = bp[dw]; bu0.y = bp[dw + 1]; bu0.z = bp[dw + 2]; bu0.w = bp[dw + 3];
                    dw += 32;
                    bu1.x = bp[dw]; bu1.y = bp[dw + 1]; bu1.z = bp[dw + 2]; bu1.w = bp[dw + 3];
                }
                v8bf B0 = __builtin_bit_cast(v8bf, bu0);
                v8bf B1 = __builtin_bit_cast(v8bf, bu1);
                acc[0][0] = __builtin_amdgcn_mfma_f32_32x32x16_bf16(A0, B0, acc[0][0], 0, 0, 0);
                acc[0][1] = __builtin_amdgcn_mfma_f32_32x32x16_bf16(A0, B1, acc[0][1], 0, 0, 0);
                acc[1][0] = __builtin_amdgcn_mfma_f32_32x32x16_bf16(A1, B0, acc[1][0], 0, 0, 0);
                acc[1][1] = __builtin_amdgcn_mfma_f32_32x32x16_bf16(A1, B1, acc[1][1], 0, 0, 0);
            }
        }

        // ---- write staged row into the other buffer, then barrier ----
        if (sv) {
            *(uint4*)(&srow[p ^ 1][wv][4 * lane]) = m;
            if (lane < 2) *(uint4*)(&srow[p ^ 1][wv][256 + 4 * lane]) = e;
        }
        __syncthreads();
    }

    // ---- epilogue: BN + hardtanh + mask, write xg[b][h][w][c] bf16 ----
    const int l1 = lens1[b];
#pragma unroll
    for (int hh = 0; hh < 2; ++hh) {
        if (hh == 1 && !h1ok) break;
        const int h = h0 + hh;
#pragma unroll
        for (int nt = 0; nt < 2; ++nt) {
            const int w = w0 + wv * 64 + nt * 32 + l31;
            const bool keep = (w < l1);
            unsigned short* dp = xg + (((size_t)b * H1_ + h) * W1_ + w) * 32;
#pragma unroll
            for (int rq = 0; rq < 4; ++rq) {
                unsigned int wd[2];
#pragma unroll
                for (int d = 0; d < 2; ++d) {
                    int rg = rq * 4 + d * 2;
                    int oc = 8 * rq + 4 * lhi + d * 2;
                    float av0 = acc[hh][nt][rg];
                    float av1 = acc[hh][nt][rg + 1];
                    float v0 = fminf(fmaxf(fmaf(av0, scsh[oc],     scsh[32 + oc]), 0.f), 20.f);
                    float v1 = fminf(fmaxf(fmaf(av1, scsh[oc + 1], scsh[33 + oc]), 0.f), 20.f);
                    if (!keep) { v0 = 0.f; v1 = 0.f; }
                    wd[d] = (unsigned int)f2bf(v0) | ((unsigned int)f2bf(v1) << 16);
                }
                uint2 u; u.x = wd[0]; u.y = wd[1];
                *(uint2*)(dp + 8 * rq + 4 * lhi) = u;
            }
        }
    }
}

// ---------------------------------------------------------------------------
// Conv2 v14 (unchanged — session-best 338 µs): 512-thread wave-specialized
// full-row block. Waves 0-3 = consumers (one per SIMD), acc[2][4], nt=4;
// waves 4-7 = producers staging the full 522-position row; single LDS
// buffer + producer register double-buffer, 2 barriers/row.
// ---------------------------------------------------------------------------
#define ROW2 41760   // 522 positions * 80 B (single buffer)

__global__ __launch_bounds__(512, 2) void conv2_mfma(
    const unsigned short* __restrict__ xg,   // [32][81][512][32] bf16
    const unsigned short* __restrict__ wf2,  // frag-ordered, kh-padded (25)
    const float* __restrict__ scsh,
    const int* __restrict__ lens1,
    float* __restrict__ out)                 // [32][32][41][512] fp32
{
    const int t    = threadIdx.x;
    const int lane = t & 63;
    const int l31  = lane & 31;
    const int lhi  = lane >> 5;
    const int wv   = t >> 6;                 // 0..3 consumers, 4..7 producers

    // bijective XCD swizzle: grid 672 = 8 * 84
    const int id  = blockIdx.x;
    const int sid = (id & 7) * 84 + (id >> 3);
    const int hp  = sid % 21;
    const int b   = sid / 21;
    const int h0  = hp * 2;
    const bool h1ok = (h0 + 1) < H2_;

    __shared__ __align__(16) char sbuf[ROW2];

    const unsigned short* xb = xg + (size_t)b * (H1_ * W1_ * 32);
    const int r0 = 2 * h0 - 10;

    if (wv >= 4) {
        // ======================= PRODUCER PATH =======================
        const int pt = t - 256;              // 0..255

        if (r0 >= 0 && r0 < H1_) {
            const char* xrow = (const char*)(xb + (size_t)r0 * (W1_ * 32));
#pragma unroll
            for (int i = 0; i < 9; ++i) {
                const int c   = pt + 256 * i;
                if (c >= 2088) break;
                const int pos = c >> 2;
                const int sg  = c & 3;
                const int wp  = pos - 5;
                uint4 z; z.x = z.y = z.z = z.w = 0u;
                if (wp >= 0 && wp < W1_)
                    z = *(const uint4*)(xrow + wp * 64 + sg * 16);
                *(uint4*)(sbuf + pos * 80 + sg * 16) = z;
            }
        }
        __syncthreads();                     // buffer ready for kp=0

        for (int kp = 0; kp < 23; ++kp) {
            const int rn = r0 + kp + 1;
            const bool sv = (kp < 22) && (rn >= 0) && (rn < H1_);
            uint4 g[9];
#pragma unroll
            for (int i = 0; i < 9; ++i) { g[i].x = g[i].y = g[i].z = g[i].w = 0u; }
            if (sv) {
                const char* xrow = (const char*)(xb + (size_t)rn * (W1_ * 32));
#pragma unroll
                for (int i = 0; i < 9; ++i) {
                    const int c   = pt + 256 * i;
                    if (c >= 2088) break;
                    const int pos = c >> 2;
                    const int sg  = c & 3;
                    const int wp  = pos - 5;
                    if (wp >= 0 && wp < W1_)
                        g[i] = *(const uint4*)(xrow + wp * 64 + sg * 16);
                }
            }
            __syncthreads();                 // A: consumers done reading row kp
            if (sv) {
#pragma unroll
                for (int i = 0; i < 9; ++i) {
                    const int c   = pt + 256 * i;
                    if (c >= 2088) break;
                    const int pos = c >> 2;
                    const int sg  = c & 3;
                    *(uint4*)(sbuf + pos * 80 + sg * 16) = g[i];
                }
            }
            __syncthreads();                 // B: row kp+1 visible
        }
        // producers exit
    } else {
        // ======================= CONSUMER PATH =======================
        v16f acc[2][4];
#pragma unroll
        for (int hh = 0; hh < 2; ++hh)
#pragma unroll
            for (int nt = 0; nt < 4; ++nt)
#pragma unroll
                for (int q = 0; q < 16; ++q) acc[hh][nt][q] = 0.f;

        const int rd_lds = (wv * 128 + l31) * 80 + lhi * 16;
        const uint4* wq  = (const uint4*)wf2;

        __syncthreads();                     // matches producer prologue barrier

        for (int kp = 0; kp < 23; ++kp) {
            const int r = r0 + kp;
            if (r >= 0 && r < H1_) {
                const int f0 = (kp + 2) * 22;
                const int f1 = kp * 22;
                const char* bbase = sbuf + rd_lds;
                __builtin_amdgcn_s_setprio(1);
#pragma unroll
                for (int kw = 0; kw < 11; ++kw) {
#pragma unroll
                    for (int ch = 0; ch < 2; ++ch) {
                        uint4 a0u = wq[(f0 + kw * 2 + ch) * 64 + lane];
                        uint4 a1u = wq[(f1 + kw * 2 + ch) * 64 + lane];
                        v8bf A0 = __builtin_bit_cast(v8bf, a0u);
                        v8bf A1 = __builtin_bit_cast(v8bf, a1u);
                        uint4 b0u = *(const uint4*)(bbase + kw * 80 + ch * 32);
                        uint4 b1u = *(const uint4*)(bbase + 2560 + kw * 80 + ch * 32);
                        uint4 b2u = *(const uint4*)(bbase + 5120 + kw * 80 + ch * 32);
                        uint4 b3u = *(const uint4*)(bbase + 7680 + kw * 80 + ch * 32);
                        v8bf B0 = __builtin_bit_cast(v8bf, b0u);
                        v8bf B1 = __builtin_bit_cast(v8bf, b1u);
                        v8bf B2 = __builtin_bit_cast(v8bf, b2u);
                        v8bf B3 = __builtin_bit_cast(v8bf, b3u);
                        acc[0][0] = __builtin_amdgcn_mfma_f32_32x32x16_bf16(A0, B0, acc[0][0], 0, 0, 0);
                        acc[0][1] = __builtin_amdgcn_mfma_f32_32x32x16_bf16(A0, B1, acc[0][1], 0, 0, 0);
                        acc[0][2] = __builtin_amdgcn_mfma_f32_32x32x16_bf16(A0, B2, acc[0][2], 0, 0, 0);
                        acc[0][3] = __builtin_amdgcn_mfma_f32_32x32x16_bf16(A0, B3, acc[0][3], 0, 0, 0);
                        acc[1][0] = __builtin_amdgcn_mfma_f32_32x32x16_bf16(A1, B0, acc[1][0], 0, 0, 0);
                        acc[1][1] = __builtin_amdgcn_mfma_f32_32x32x16_bf16(A1, B1, acc[1][1], 0, 0, 0);
                        acc[1][2] = __builtin_amdgcn_mfma_f32_32x32x16_bf16(A1, B2, acc[1][2], 0, 0, 0);
                        acc[1][3] = __builtin_amdgcn_mfma_f32_32x32x16_bf16(A1, B3, acc[1][3], 0, 0, 0);
                    }
                }
                __builtin_amdgcn_s_setprio(0);
            }
            __syncthreads();                 // A
            __syncthreads();                 // B
        }

        // ---- epilogue: BN + hardtanh + mask (consumers only) ----
        const int l2 = lens1[b];
#pragma unroll
        for (int hh = 0; hh < 2; ++hh) {
            if (hh == 1 && !h1ok) break;
            const int h = h0 + hh;
#pragma unroll
            for (int nt = 0; nt < 4; ++nt) {
                const int w = wv * 128 + nt * 32 + l31;
                const bool keep = (w < l2);
#pragma unroll
                for (int reg = 0; reg < 16; ++reg) {
                    const int oc = (reg & 3) + 8 * (reg >> 2) + 4 * lhi;
                    float v = fmaf(acc[hh][nt][reg], scsh[64 + oc], scsh[96 + oc]);
                    v = fminf(fmaxf(v, 0.f), 20.f);
                    out[(((size_t)b * C2_ + oc) * H2_ + h) * W2_ + w] = keep ? v : 0.f;
                }
            }
        }
    }
}

// ---------------------------------------------------------------------------
extern "C" void kernel_launch(void* const* d_in, const int* in_sizes, int n_in,
                              void* d_out, int out_size, void* d_ws, size_t ws_size,
                              hipStream_t stream) {
    const float* inputs = (const float*)d_in[0];
    const int*   slen   = (const int*)d_in[1];
    const float* w1 = (const float*)d_in[2];
    const float* b1 = (const float*)d_in[3];
    const float* g1 = (const float*)d_in[4];
    const float* be1 = (const float*)d_in[5];
    const float* m1 = (const float*)d_in[6];
    const float* v1 = (const float*)d_in[7];
    const float* w2 = (const float*)d_in[8];
    const float* b2 = (const float*)d_in[9];
    const float* g2 = (const float*)d_in[10];
    const float* be2 = (const float*)d_in[11];
    const float* m2 = (const float*)d_in[12];
    const float* v2 = (const float*)d_in[13];

    char* ws = (char*)d_ws;
    unsigned short* wf2  = (unsigned short*)(ws + WF2_B);
    unsigned short* wf1  = (unsigned short*)(ws + WF1_B);
    float*          scsh = (float*)(ws + SCSH_B);
    int*            lens1 = (int*)(ws + LENS1_B);
    unsigned short* xg   = (unsigned short*)(ws + XG_B);

    float* out_x    = (float*)d_out;
    float* out_lens = out_x + OUT_X_SZ;

    // xpk scratch aliases the start of d_out (10.72 MB); conv2 overwrites
    // the whole out_x region afterwards (stream-ordered).
    unsigned int* xpk = (unsigned int*)d_out;

    hipLaunchKernelGGL(prep_kernel, dim3(256), dim3(256), 0, stream,
                       w1, b1, g1, be1, m1, v1, w2, b2, g2, be2, m2, v2,
                       slen, wf1, wf2, scsh, lens1, out_lens);

    // xcvt: 32*161 = 5152 rows, one block per row
    hipLaunchKernelGGL(xcvt_kernel, dim3(B_ * H_IN), dim3(256), 0, stream,
                       inputs, xpk);

    // conv1: 2 w-halves x 41 h-pairs x 32 b (v15: xpk-fed staging)
    hipLaunchKernelGGL(conv1_mfma, dim3(2, 41, B_), dim3(256), 0, stream,
                       xpk, wf1, scsh, lens1, xg);

    // conv2: 32 b * 21 h-pairs = 672 blocks (8*84, XCD-swizzled),
    // 512 threads: 4 consumer waves (one per SIMD) + 4 producer waves
    hipLaunchKernelGGL(conv2_mfma, dim3(672), dim3(512), 0, stream,
                       xg, wf2, scsh, lens1, out_x);
}